// Round 13
// baseline (228.809 us; speedup 1.0000x reference)
//
#include <hip/hip_runtime.h>
#include <hip/hip_bf16.h>

#define BB 8
#define NN 16384
#define D1 256
#define D2 64
#define DT 320
#define EPSF 1e-12f
#define NCG 16          // K chunks
#define KCH 1024        // rows per chunk
#define TILE 128        // rows per phase (2 sub-tiles of 64)
#define NPH (KCH/TILE)  // 8 phases
#define QSZ (160*320)   // partial slice elems

typedef __attribute__((ext_vector_type(8))) short bf16x8;
typedef __attribute__((ext_vector_type(8))) unsigned short u16x8;
typedef __attribute__((ext_vector_type(4))) float f32x4;
typedef __attribute__((ext_vector_type(4))) unsigned int u32x4;

__device__ __forceinline__ unsigned int packbf2(float a, float b) {
    unsigned short lo = __builtin_bit_cast(unsigned short, __float2bfloat16(a));
    unsigned short hi = __builtin_bit_cast(unsigned short, __float2bfloat16(b));
    return (unsigned int)lo | ((unsigned int)hi << 16);
}
__device__ __forceinline__ unsigned short f2bfu(float f) {
    return __builtin_bit_cast(unsigned short, __float2bfloat16(f));
}
__device__ __forceinline__ float bf2f(unsigned short u) {
    unsigned int x = (unsigned int)u << 16;
    return __builtin_bit_cast(float, x);
}

// 8-unit swizzle over [c][64-row] bf16 sub-tile (128B rows): element (c, n8*8+k)
// -> unit u = (n8 ^ sig(c)) & 7. Conflict-clean for b128 staging writes and
// <=2-way for b128 frag reads. [R3/R6-verified]
__device__ __forceinline__ int sig(int c) { return (c ^ (c >> 2)) & 7; }

// ---------------- kernel 1: s[b,c] = sum_n Y[b,n,c] ----------------
__global__ void colsum_kernel(const float* __restrict__ Y, float* __restrict__ s) {
    const int b = blockIdx.y;
    const int chunk = blockIdx.x;
    const int t = threadIdx.x;
    const int c = t & 63;
    const int r = t >> 6;
    const float* Yb = Y + (size_t)b * NN * D2;
    float acc = 0.f;
    const int nbase = chunk * 512;
    for (int k = 0; k < 128; ++k) {
        int n = nbase + k * 4 + r;
        acc += Yb[(size_t)n * D2 + c];
    }
    __shared__ float red[256];
    red[t] = acc;
    __syncthreads();
    if (r == 0) {
        float v = red[c] + red[64 + c] + red[128 + c] + red[192 + c];
        atomicAdd(&s[b * D2 + c], v);
    }
}

// ---------------- kernel 2: rsd[b,n] = (Y[b,n,:].s[b,:] + eps)^(-1/4) ----------------
__global__ void rsd_kernel(const float* __restrict__ Y, const float* __restrict__ s,
                           float* __restrict__ rsd) {
    const int blk = blockIdx.x;
    const int b = blk >> 8;
    const int nb = (blk & 255) * 64;
    const int t = threadIdx.x;
    const int q = t & 3;
    const int nl = t >> 2;
    __shared__ float ss[D2];
    if (t < D2) ss[t] = s[b * D2 + t];
    __syncthreads();
    const int n = nb + nl;
    const float* yrow = Y + (size_t)b * NN * D2 + (size_t)n * D2 + q * 16;
    float dot = 0.f;
#pragma unroll
    for (int i = 0; i < 4; ++i) {
        float4 f = *reinterpret_cast<const float4*>(yrow + i * 4);
        const float* sp = ss + q * 16 + i * 4;
        dot += f.x * sp[0] + f.y * sp[1] + f.z * sp[2] + f.w * sp[3];
    }
    dot += __shfl_xor(dot, 1);
    dot += __shfl_xor(dot, 2);
    if (q == 0) {
        rsd[(size_t)b * NN + n] = rsqrtf(sqrtf(dot + EPSF));
    }
}

// ---------------- staging helpers (R6-verified, verbatim) ----------------
__device__ __forceinline__ void issue_loads(const float* __restrict__ Vb,
                                            const float* __restrict__ Yb,
                                            const float* __restrict__ rb,
                                            int r0, int lane,
                                            float4* vf, float4* yf, float* rr) {
#pragma unroll
    for (int j = 0; j < 8; ++j)
        vf[j] = *reinterpret_cast<const float4*>(Vb + (size_t)(r0 + j) * D1 + 4 * lane);
    const int j2 = lane >> 4, k15 = lane & 15;
    yf[0] = *reinterpret_cast<const float4*>(Yb + (size_t)(r0 + 2 * j2) * D2 + 4 * k15);
    yf[1] = *reinterpret_cast<const float4*>(Yb + (size_t)(r0 + 2 * j2 + 1) * D2 + 4 * k15);
#pragma unroll
    for (int j = 0; j < 8; ++j) rr[j] = rb[r0 + j];
}

__device__ __forceinline__ void write_tile(unsigned short* __restrict__ x,
                                           int lane, int n8,
                                           const float4* vf, const float4* yf,
                                           const float* rr) {
    const float* vfp = reinterpret_cast<const float*>(vf);
    const float* yfp = reinterpret_cast<const float*>(yf);
#pragma unroll
    for (int cidx = 0; cidx < 4; ++cidx) {
        const int c = 4 * lane + cidx;
        const int u = (n8 ^ sig(c)) & 7;
        u32x4 p;
        p[0] = packbf2(vfp[0 * 4 + cidx] * rr[0], vfp[1 * 4 + cidx] * rr[1]);
        p[1] = packbf2(vfp[2 * 4 + cidx] * rr[2], vfp[3 * 4 + cidx] * rr[3]);
        p[2] = packbf2(vfp[4 * 4 + cidx] * rr[4], vfp[5 * 4 + cidx] * rr[5]);
        p[3] = packbf2(vfp[6 * 4 + cidx] * rr[6], vfp[7 * 4 + cidx] * rr[7]);
        *reinterpret_cast<u32x4*>(&x[c * 64 + u * 8]) = p;
    }
    const int j2 = lane >> 4, k15 = lane & 15;
    const float r0 = rr[2 * j2], r1 = rr[2 * j2 + 1];
#pragma unroll
    for (int cidx = 0; cidx < 4; ++cidx) {
        const int c = D1 + 4 * k15 + cidx;
        const int u = (n8 ^ sig(c)) & 7;
        unsigned int p = packbf2(yfp[cidx] * r0, yfp[4 + cidx] * r1);
        *reinterpret_cast<unsigned int*>(&x[c * 64 + u * 8 + j2 * 2]) = p;
    }
}

// ---------------- kernel 3: band Gram, 128-row phases, 1 block/CU ----------------
// grid (16 cg, 2 band, 8 b) = 256 blocks; 512 thr (8 waves: 2x4 of 80x80).
// Phase = two stacked R6 64-row sub-tiles (80 KB LDS). Loads for t+1 issue
// before MFMA(t); pack+write after the post-MFMA barrier. 8 phases total.
__global__ void __launch_bounds__(512, 2)
gram6_kernel(const float* __restrict__ V, const float* __restrict__ Y,
             const float* __restrict__ rsd, unsigned short* __restrict__ Gpart,
             float* __restrict__ Gfull, int priv) {
    const int cg = blockIdx.x;
    const int band = blockIdx.y;
    const int b = blockIdx.z;
    const int t = threadIdx.x;
    const int lane = t & 63;
    const int w = t >> 6;          // 0..7
    const int wrow = w >> 2;       // 0..1
    const int wcol = w & 3;        // 0..3
    const int l15 = lane & 15;
    const int l4 = lane >> 4;
    const int hs = w >> 2;         // staging: sub-tile this wave fills
    const int wl = w & 3;          // octet pair within sub-tile

    const float* Vb = V + (size_t)b * NN * D1;
    const float* Yb = Y + (size_t)b * NN * D2;
    const float* rb = rsd + (size_t)b * NN;

    __shared__ __attribute__((aligned(16))) unsigned short xb[2][DT * 64];  // 80 KB

    f32x4 acc[5][5];
#pragma unroll
    for (int i = 0; i < 5; ++i)
#pragma unroll
        for (int j = 0; j < 5; ++j)
            acc[i][j] = (f32x4){0.f, 0.f, 0.f, 0.f};

    float4 vfA[8], vfB[8];
    float4 yfA[2], yfB[2];
    float rrA[8], rrB[8];

    const int n0base = cg * KCH;
    const int rbase = hs * 64 + wl * 16;       // this wave's first row in a phase

    // prologue: stage phase 0
    issue_loads(Vb, Yb, rb, n0base + rbase, lane, vfA, yfA, rrA);
    issue_loads(Vb, Yb, rb, n0base + rbase + 8, lane, vfB, yfB, rrB);
    write_tile(xb[hs], lane, 2 * wl, vfA, yfA, rrA);
    write_tile(xb[hs], lane, 2 * wl + 1, vfB, yfB, rrB);
    __syncthreads();

    for (int tt = 0; tt < NPH; ++tt) {
        if (tt < NPH - 1) {   // issue next phase's loads; hidden under MFMA
            const int r0 = n0base + (tt + 1) * TILE + rbase;
            issue_loads(Vb, Yb, rb, r0, lane, vfA, yfA, rrA);
            issue_loads(Vb, Yb, rb, r0 + 8, lane, vfB, yfB, rrB);
        }

#pragma unroll
        for (int s = 0; s < 2; ++s) {
            const unsigned short* x = xb[s];
#pragma unroll
            for (int ks = 0; ks < 2; ++ks) {
                const int n8r = 2 * l4 + ks;   // K-block remap, A/B consistent [R6]
                bf16x8 af[5], bfr[5];
#pragma unroll
                for (int i = 0; i < 5; ++i) {
                    const int ca = band * 160 + wrow * 80 + i * 16 + l15;
                    af[i] = *reinterpret_cast<const bf16x8*>(
                        &x[ca * 64 + ((n8r ^ sig(ca)) & 7) * 8]);
                    const int cb = wcol * 80 + i * 16 + l15;
                    bfr[i] = *reinterpret_cast<const bf16x8*>(
                        &x[cb * 64 + ((n8r ^ sig(cb)) & 7) * 8]);
                }
#pragma unroll
                for (int i = 0; i < 5; ++i)
#pragma unroll
                    for (int j = 0; j < 5; ++j)
                        acc[i][j] = __builtin_amdgcn_mfma_f32_16x16x32_bf16(
                            af[i], bfr[j], acc[i][j], 0, 0, 0);
            }
        }

        __syncthreads();               // MFMA reads of this phase done
        if (tt < NPH - 1) {
            write_tile(xb[hs], lane, 2 * wl, vfA, yfA, rrA);
            write_tile(xb[hs], lane, 2 * wl + 1, vfB, yfB, rrB);
        }
        __syncthreads();               // next tile visible
    }

    if (priv) {
        // bf16 partial [160][320], slice (b*2+band)*NCG+cg   [R6-verified mapping]
        unsigned short* Gp = Gpart + (size_t)((b * 2 + band) * NCG + cg) * QSZ;
#pragma unroll
        for (int i = 0; i < 5; ++i) {
            const int gi_base = wrow * 80 + i * 16 + l4 * 4;
#pragma unroll
            for (int j = 0; j < 5; ++j) {
                const int gj = wcol * 80 + j * 16 + l15;
#pragma unroll
                for (int rg = 0; rg < 4; ++rg)
                    Gp[(size_t)(gi_base + rg) * DT + gj] = f2bfu(acc[i][j][rg]);
            }
        }
    } else {
        float* Gb = Gfull + (size_t)b * DT * DT;
#pragma unroll
        for (int i = 0; i < 5; ++i) {
            const int gi_base = band * 160 + wrow * 80 + i * 16 + l4 * 4;
#pragma unroll
            for (int j = 0; j < 5; ++j) {
                const int gj = wcol * 80 + j * 16 + l15;
#pragma unroll
                for (int rg = 0; rg < 4; ++rg)
                    atomicAdd(&Gb[(size_t)(gi_base + rg) * DT + gj], acc[i][j][rg]);
            }
        }
    }
}

// ---------------- kernel 4: reduce NCG bf16 partials [R10-verified, NCG=16] ------
__global__ void loss_priv_kernel(const unsigned short* __restrict__ Gpart,
                                 float* __restrict__ out) {
    const int by = blockIdx.y;             // b*2 + band
    const int band = by & 1;
    const int t = threadIdx.x;
    const int e0 = (blockIdx.x * 256 + t) * 8;
    float g[8];
#pragma unroll
    for (int k = 0; k < 8; ++k) g[k] = 0.f;
    const unsigned short* base = Gpart + (size_t)by * NCG * QSZ + e0;
#pragma unroll 4
    for (int cg = 0; cg < NCG; ++cg) {
        u16x8 p = *reinterpret_cast<const u16x8*>(base + (size_t)cg * QSZ);
#pragma unroll
        for (int k = 0; k < 8; ++k) g[k] += bf2f(p[k]);
    }
    const int ii = e0 / DT;
    const int jj = e0 - ii * DT;
    const int ig = band * 160 + ii;
    const float wgt = ((ig < D1) == (jj < D1)) ? 1.f : -1.f;
    float sum = 0.f;
#pragma unroll
    for (int k = 0; k < 8; ++k) sum += g[k] * g[k];
    sum *= wgt;
#pragma unroll
    for (int off = 1; off < 64; off <<= 1) sum += __shfl_xor(sum, off);
    __shared__ float red[4];
    if ((t & 63) == 0) red[t >> 6] = sum;
    __syncthreads();
    if (t == 0) atomicAdd(out, (red[0] + red[1] + red[2] + red[3]) * 0.125f);
}

// ---------------- kernel 4b: fallback loss over accumulated full G ----------------
__global__ void loss_kernel(const float* __restrict__ G, float* __restrict__ out) {
    const int b = blockIdx.x >> 3;
    const int slice = blockIdx.x & 7;
    const int t = threadIdx.x;
    const float* Gb = G + (size_t)b * DT * DT;
    float sum = 0.f;
    for (int k = 0; k < 50; ++k) {
        const int e = slice * 12800 + k * 256 + t;
        const int i = e / DT;
        const int j = e - i * DT;
        const float gv = Gb[e];
        const float w = ((i < D1) == (j < D1)) ? 1.f : -1.f;
        sum += w * gv * gv;
    }
#pragma unroll
    for (int off = 1; off < 64; off <<= 1) sum += __shfl_xor(sum, off);
    __shared__ float red[4];
    if ((t & 63) == 0) red[t >> 6] = sum;
    __syncthreads();
    if (t == 0) atomicAdd(out, (red[0] + red[1] + red[2] + red[3]) * 0.125f);
}

extern "C" void kernel_launch(void* const* d_in, const int* in_sizes, int n_in,
                              void* d_out, int out_size, void* d_ws, size_t ws_size,
                              hipStream_t stream) {
    const float* V = (const float*)d_in[0];
    const float* Y = (const float*)d_in[1];
    float* out = (float*)d_out;

    char* ws = (char*)d_ws;
    float* s   = (float*)ws;                          // 2048 B
    float* rsd = (float*)(ws + 2048);                 // 524288 B

    const size_t GP_OFF = 2048 + 524288;
    const size_t GP_BYTES = (size_t)BB * 2 * NCG * QSZ * 2;   // 26.2 MB
    const int priv = (ws_size >= GP_OFF + GP_BYTES) ? 1 : 0;

    hipMemsetAsync(s, 0, 2048, stream);
    hipMemsetAsync(d_out, 0, sizeof(float), stream);

    colsum_kernel<<<dim3(32, BB), 256, 0, stream>>>(Y, s);
    rsd_kernel<<<2048, 256, 0, stream>>>(Y, s, rsd);

    if (priv) {
        unsigned short* Gpart = (unsigned short*)(ws + GP_OFF);
        gram6_kernel<<<dim3(NCG, 2, BB), 512, 0, stream>>>(V, Y, rsd, Gpart, nullptr, 1);
        loss_priv_kernel<<<dim3(25, 16), 256, 0, stream>>>(Gpart, out);
    } else {
        float* Gfull = (float*)(ws + GP_OFF);
        hipMemsetAsync(Gfull, 0, (size_t)BB * DT * DT * 4, stream);
        gram6_kernel<<<dim3(NCG, 2, BB), 512, 0, stream>>>(V, Y, rsd, nullptr, Gfull, 0);
        loss_kernel<<<64, 256, 0, stream>>>(Gfull, out);
    }
}

// Round 14
// 97.992 us; speedup vs baseline: 2.3350x; 2.3350x over previous
//
#include <hip/hip_runtime.h>
#include <hip/hip_bf16.h>

#define BB 8
#define NN 16384
#define D1 256
#define D2 64
#define DT 320
#define EPSF 1e-12f
#define NCG 16          // K chunks
#define KCH 1024        // rows per chunk (16 tiles of 64)
#define QSZ (160*320)   // partial slice elems

typedef __attribute__((ext_vector_type(8))) short bf16x8;
typedef __attribute__((ext_vector_type(8))) unsigned short u16x8;
typedef __attribute__((ext_vector_type(4))) float f32x4;
typedef __attribute__((ext_vector_type(4))) unsigned int u32x4;

__device__ __forceinline__ unsigned int packbf2(float a, float b) {
    unsigned short lo = __builtin_bit_cast(unsigned short, __float2bfloat16(a));
    unsigned short hi = __builtin_bit_cast(unsigned short, __float2bfloat16(b));
    return (unsigned int)lo | ((unsigned int)hi << 16);
}
__device__ __forceinline__ unsigned short f2bfu(float f) {
    return __builtin_bit_cast(unsigned short, __float2bfloat16(f));
}
__device__ __forceinline__ float bf2f(unsigned short u) {
    unsigned int x = (unsigned int)u << 16;
    return __builtin_bit_cast(float, x);
}

// 8-unit swizzle over [c][64-row] bf16 tile: element (c, n8*8+k) lives at unit
// u = (n8 ^ sig(c)) & 7 of row c. [R3/R6-verified clean for frag reads]
__device__ __forceinline__ int sig(int c) { return (c ^ (c >> 2)) & 7; }

// validated in R7/R10: per-lane global src, wave-uniform LDS base + lane*16
__device__ __forceinline__ void gload16(const unsigned short* g, unsigned short* l) {
    __builtin_amdgcn_global_load_lds(
        (const __attribute__((address_space(1))) unsigned int*)(g),
        (__attribute__((address_space(3))) unsigned int*)(l), 16, 0, 0);
}

// ---------------- kernel 1: s[b,c] = sum_n Y[b,n,c] ----------------
__global__ void colsum_kernel(const float* __restrict__ Y, float* __restrict__ s) {
    const int b = blockIdx.y;
    const int chunk = blockIdx.x;
    const int t = threadIdx.x;
    const int c = t & 63;
    const int r = t >> 6;
    const float* Yb = Y + (size_t)b * NN * D2;
    float acc = 0.f;
    const int nbase = chunk * 512;
    for (int k = 0; k < 128; ++k) {
        int n = nbase + k * 4 + r;
        acc += Yb[(size_t)n * D2 + c];
    }
    __shared__ float red[256];
    red[t] = acc;
    __syncthreads();
    if (r == 0) {
        float v = red[c] + red[64 + c] + red[128 + c] + red[192 + c];
        atomicAdd(&s[b * D2 + c], v);
    }
}

// ---------------- kernel 2: rsd[b,n] = (Y[b,n,:].s[b,:] + eps)^(-1/4) ----------------
__global__ void rsd_kernel(const float* __restrict__ Y, const float* __restrict__ s,
                           float* __restrict__ rsd) {
    const int blk = blockIdx.x;
    const int b = blk >> 8;
    const int nb = (blk & 255) * 64;
    const int t = threadIdx.x;
    const int q = t & 3;
    const int nl = t >> 2;
    __shared__ float ss[D2];
    if (t < D2) ss[t] = s[b * D2 + t];
    __syncthreads();
    const int n = nb + nl;
    const float* yrow = Y + (size_t)b * NN * D2 + (size_t)n * D2 + q * 16;
    float dot = 0.f;
#pragma unroll
    for (int i = 0; i < 4; ++i) {
        float4 f = *reinterpret_cast<const float4*>(yrow + i * 4);
        const float* sp = ss + q * 16 + i * 4;
        dot += f.x * sp[0] + f.y * sp[1] + f.z * sp[2] + f.w * sp[3];
    }
    dot += __shfl_xor(dot, 1);
    dot += __shfl_xor(dot, 2);
    if (q == 0) {
        rsd[(size_t)b * NN + n] = rsqrtf(sqrtf(dot + EPSF));
    }
}

// ---------------- kernel 3: Xs = scaled bf16 tiles in gram-ready swizzled layout ----
// Xs tile (b, nt): 40 KB = [c=0..319][u=0..7][k=0..7], value X[n][c]*rsd[n],
// n = nt*64 + 8*(u^sig(c)) + k.  grid (256 nt, 5 cseg, 8 b), 256 thr.  [R10-verified]
__global__ void xt2_kernel(const float* __restrict__ V, const float* __restrict__ Y,
                           const float* __restrict__ rsd, unsigned short* __restrict__ Xs) {
    const int nt = blockIdx.x;
    const int cs = blockIdx.y;
    const int b = blockIdx.z;
    const int t = threadIdx.x;
    const int n0 = nt * 64;
    const int r = t >> 2;           // local row 0..63
    const int cq = t & 3;           // 16-col group
    const bool isY = (cs == 4);
    const int c0g = isY ? D1 : cs * 64;      // global col base of this 64-col slab

    const int n = n0 + r;
    const float sc = rsd[(size_t)b * NN + n];
    const float* srow = isY
        ? (Y + ((size_t)b * NN + n) * D2 + cq * 16)
        : (V + ((size_t)b * NN + n) * D1 + cs * 64 + cq * 16);

    __shared__ __attribute__((aligned(16))) unsigned short tile[64 * 64];  // 8 KB

    const int k = r & 7;
    const int n8 = r >> 3;
#pragma unroll
    for (int ii = 0; ii < 4; ++ii) {
        float4 f = *reinterpret_cast<const float4*>(srow + ii * 4);
        const float* fp = &f.x;
#pragma unroll
        for (int e = 0; e < 4; ++e) {
            const int cl = cq * 16 + ii * 4 + e;          // local col 0..63
            const int u = (n8 ^ sig(c0g + cl)) & 7;
            tile[cl * 64 + u * 8 + k] = f2bfu(fp[e] * sc);
        }
    }
    __syncthreads();

    // dump 8 KB slab -> Xs tile rows [c0g, c0g+64)
    unsigned short* out = Xs + ((size_t)(b * 256 + nt) * DT + c0g) * 64;
#pragma unroll
    for (int q = 0; q < 2; ++q) {
        const int off = (q * 256 + t) * 8;
        *reinterpret_cast<u32x4*>(out + off) =
            *reinterpret_cast<const u32x4*>(&tile[off]);
    }
}

// ---------------- kernel 4: band Gram from Xs via global_load_lds -----------------
// grid (16 cg, 2 band, 8 b) = 256 blocks = 1/CU; 512 thr (8 waves 2x4 of 80x80).
// Staging = 5 async DMA per wave per tile, double-buffered, loads in flight
// across the MFMA phase (m97 structure). __launch_bounds__(512,2): cap 256 regs
// (acc 100 AGPR + frags 40 + addr ~20 fits) -- THE fix for R10's 64-cap spill.
__global__ void __launch_bounds__(512, 2)
gram4_kernel(const unsigned short* __restrict__ Xs,
             unsigned short* __restrict__ Gpart) {
    const int cg = blockIdx.x;
    const int band = blockIdx.y;
    const int b = blockIdx.z;
    const int t = threadIdx.x;
    const int lane = t & 63;
    const int w = t >> 6;
    const int wrow = w >> 2;
    const int wcol = w & 3;
    const int l15 = lane & 15;
    const int l4 = lane >> 4;

    __shared__ __attribute__((aligned(16))) unsigned short xb[2][DT * 64];  // 80 KB

    f32x4 acc[5][5];
#pragma unroll
    for (int i = 0; i < 5; ++i)
#pragma unroll
        for (int j = 0; j < 5; ++j)
            acc[i][j] = (f32x4){0.f, 0.f, 0.f, 0.f};

    const int nt0 = cg * (KCH / 64);
    const size_t Xb = (size_t)b * 256 * DT * 64;

    // stage tile nt into buf: per wave 5 x 1KB DMA, linear copy (swizzle pre-baked)
#define STAGE4(buf, nt)                                                          \
    {                                                                            \
        const unsigned short* tb = Xs + Xb + (size_t)(nt) * (DT * 64);           \
        _Pragma("unroll")                                                        \
        for (int rql = 0; rql < 5; ++rql) {                                      \
            const int eo = (w * 5 + rql) * 512;                                  \
            gload16(tb + eo + lane * 8, &xb[buf][eo]);                           \
        }                                                                        \
    }

    STAGE4(0, nt0);
    __syncthreads();                 // vmcnt drained -> tile 0 resident

    int cur = 0;
    for (int tt = 0; tt < KCH / 64; ++tt) {
        if (tt < KCH / 64 - 1) STAGE4(cur ^ 1, nt0 + tt + 1);   // async during MFMA

        const unsigned short* x = xb[cur];
#pragma unroll
        for (int ks = 0; ks < 2; ++ks) {
            const int n8r = 2 * l4 + ks;     // K-block remap, A/B consistent [R6]
            bf16x8 af[5], bfr[5];
#pragma unroll
            for (int i = 0; i < 5; ++i) {
                const int ca = band * 160 + wrow * 80 + i * 16 + l15;
                af[i] = *reinterpret_cast<const bf16x8*>(
                    &x[ca * 64 + ((n8r ^ sig(ca)) & 7) * 8]);
                const int cb = wcol * 80 + i * 16 + l15;
                bfr[i] = *reinterpret_cast<const bf16x8*>(
                    &x[cb * 64 + ((n8r ^ sig(cb)) & 7) * 8]);
            }
#pragma unroll
            for (int i = 0; i < 5; ++i)
#pragma unroll
                for (int j = 0; j < 5; ++j)
                    acc[i][j] = __builtin_amdgcn_mfma_f32_16x16x32_bf16(
                        af[i], bfr[j], acc[i][j], 0, 0, 0);
        }
        __syncthreads();             // frag reads done + next tile's DMA drained
        cur ^= 1;
    }
#undef STAGE4

    // bf16 partial [160][320], slice (b*2+band)*NCG+cg   [R6-verified mapping]
    unsigned short* Gp = Gpart + (size_t)((b * 2 + band) * NCG + cg) * QSZ;
#pragma unroll
    for (int i = 0; i < 5; ++i) {
        const int gi_base = wrow * 80 + i * 16 + l4 * 4;
#pragma unroll
        for (int j = 0; j < 5; ++j) {
            const int gj = wcol * 80 + j * 16 + l15;
#pragma unroll
            for (int rg = 0; rg < 4; ++rg)
                Gp[(size_t)(gi_base + rg) * DT + gj] = f2bfu(acc[i][j][rg]);
        }
    }
}

// ---------------- kernel 5: reduce NCG bf16 partials -> weighted square sum -------
// grid (25, 16): y = b*2+band, x = slice of 2048 elems (8/thread)   [R10-verified]
__global__ void loss_priv_kernel(const unsigned short* __restrict__ Gpart,
                                 float* __restrict__ out) {
    const int by = blockIdx.y;
    const int band = by & 1;
    const int t = threadIdx.x;
    const int e0 = (blockIdx.x * 256 + t) * 8;
    float g[8];
#pragma unroll
    for (int k = 0; k < 8; ++k) g[k] = 0.f;
    const unsigned short* base = Gpart + (size_t)by * NCG * QSZ + e0;
#pragma unroll 4
    for (int cg = 0; cg < NCG; ++cg) {
        u16x8 p = *reinterpret_cast<const u16x8*>(base + (size_t)cg * QSZ);
#pragma unroll
        for (int k = 0; k < 8; ++k) g[k] += bf2f(p[k]);
    }
    const int ii = e0 / DT;
    const int jj = e0 - ii * DT;
    const int ig = band * 160 + ii;
    const float wgt = ((ig < D1) == (jj < D1)) ? 1.f : -1.f;
    float sum = 0.f;
#pragma unroll
    for (int k = 0; k < 8; ++k) sum += g[k] * g[k];
    sum *= wgt;
#pragma unroll
    for (int off = 1; off < 64; off <<= 1) sum += __shfl_xor(sum, off);
    __shared__ float red[4];
    if ((t & 63) == 0) red[t >> 6] = sum;
    __syncthreads();
    if (t == 0) atomicAdd(out, (red[0] + red[1] + red[2] + red[3]) * 0.125f);
}

// ================= fallback (small ws): R6-proven fused path =================
__device__ __forceinline__ void issue_loads(const float* __restrict__ Vb,
                                            const float* __restrict__ Yb,
                                            const float* __restrict__ rb,
                                            int n0w, int lane,
                                            float4* vf, float4* yf, float* rr) {
#pragma unroll
    for (int j = 0; j < 8; ++j)
        vf[j] = *reinterpret_cast<const float4*>(Vb + (size_t)(n0w + j) * D1 + 4 * lane);
    const int j2 = lane >> 4, k15 = lane & 15;
    yf[0] = *reinterpret_cast<const float4*>(Yb + (size_t)(n0w + 2 * j2) * D2 + 4 * k15);
    yf[1] = *reinterpret_cast<const float4*>(Yb + (size_t)(n0w + 2 * j2 + 1) * D2 + 4 * k15);
#pragma unroll
    for (int j = 0; j < 8; ++j) rr[j] = rb[n0w + j];
}

__device__ __forceinline__ void write_tile(unsigned short* __restrict__ x,
                                           int lane, int w,
                                           const float4* vf, const float4* yf,
                                           const float* rr) {
    const float* vfp = reinterpret_cast<const float*>(vf);
    const float* yfp = reinterpret_cast<const float*>(yf);
#pragma unroll
    for (int cidx = 0; cidx < 4; ++cidx) {
        const int c = 4 * lane + cidx;
        const int u = (w ^ sig(c)) & 7;
        u32x4 p;
        p[0] = packbf2(vfp[0 * 4 + cidx] * rr[0], vfp[1 * 4 + cidx] * rr[1]);
        p[1] = packbf2(vfp[2 * 4 + cidx] * rr[2], vfp[3 * 4 + cidx] * rr[3]);
        p[2] = packbf2(vfp[4 * 4 + cidx] * rr[4], vfp[5 * 4 + cidx] * rr[5]);
        p[3] = packbf2(vfp[6 * 4 + cidx] * rr[6], vfp[7 * 4 + cidx] * rr[7]);
        *reinterpret_cast<u32x4*>(&x[c * 64 + u * 8]) = p;
    }
    const int j2 = lane >> 4, k15 = lane & 15;
    const float r0 = rr[2 * j2], r1 = rr[2 * j2 + 1];
#pragma unroll
    for (int cidx = 0; cidx < 4; ++cidx) {
        const int c = D1 + 4 * k15 + cidx;
        const int u = (w ^ sig(c)) & 7;
        unsigned int p = packbf2(yfp[cidx] * r0, yfp[4 + cidx] * r1);
        *reinterpret_cast<unsigned int*>(&x[c * 64 + u * 8 + j2 * 2]) = p;
    }
}

__global__ void __launch_bounds__(512, 2)
gram_fb_kernel(const float* __restrict__ V, const float* __restrict__ Y,
               const float* __restrict__ rsd, unsigned short* __restrict__ Gpart) {
    const int cg = blockIdx.x;
    const int band = blockIdx.y;
    const int b = blockIdx.z;
    const int t = threadIdx.x;
    const int lane = t & 63;
    const int w = t >> 6;
    const int wrow = w >> 2;
    const int wcol = w & 3;
    const int l15 = lane & 15;
    const int l4 = lane >> 4;

    const float* Vb = V + (size_t)b * NN * D1;
    const float* Yb = Y + (size_t)b * NN * D2;
    const float* rb = rsd + (size_t)b * NN;

    __shared__ __attribute__((aligned(16))) unsigned short xt[DT * 64];

    f32x4 acc[5][5];
#pragma unroll
    for (int i = 0; i < 5; ++i)
#pragma unroll
        for (int j = 0; j < 5; ++j)
            acc[i][j] = (f32x4){0.f, 0.f, 0.f, 0.f};

    float4 vf[8];
    float4 yf[2];
    float rr[8];

    const int n0base = cg * KCH;
    issue_loads(Vb, Yb, rb, n0base + 8 * w, lane, vf, yf, rr);
    write_tile(xt, lane, w, vf, yf, rr);

    for (int tt = 0; tt < KCH / 64; ++tt) {
        __syncthreads();
        if (tt < KCH / 64 - 1)
            issue_loads(Vb, Yb, rb, n0base + (tt + 1) * 64 + 8 * w, lane, vf, yf, rr);
#pragma unroll
        for (int ks = 0; ks < 2; ++ks) {
            const int n8r = 2 * l4 + ks;
            bf16x8 af[5], bfr[5];
#pragma unroll
            for (int i = 0; i < 5; ++i) {
                const int ca = band * 160 + wrow * 80 + i * 16 + l15;
                af[i] = *reinterpret_cast<const bf16x8*>(
                    &xt[ca * 64 + ((n8r ^ sig(ca)) & 7) * 8]);
                const int cb = wcol * 80 + i * 16 + l15;
                bfr[i] = *reinterpret_cast<const bf16x8*>(
                    &xt[cb * 64 + ((n8r ^ sig(cb)) & 7) * 8]);
            }
#pragma unroll
            for (int i = 0; i < 5; ++i)
#pragma unroll
                for (int j = 0; j < 5; ++j)
                    acc[i][j] = __builtin_amdgcn_mfma_f32_16x16x32_bf16(
                        af[i], bfr[j], acc[i][j], 0, 0, 0);
        }
        __syncthreads();
        if (tt < KCH / 64 - 1)
            write_tile(xt, lane, w, vf, yf, rr);
    }

    unsigned short* Gp = Gpart + (size_t)((b * 2 + band) * NCG + cg) * QSZ;
#pragma unroll
    for (int i = 0; i < 5; ++i) {
        const int gi_base = wrow * 80 + i * 16 + l4 * 4;
#pragma unroll
        for (int j = 0; j < 5; ++j) {
            const int gj = wcol * 80 + j * 16 + l15;
#pragma unroll
            for (int rg = 0; rg < 4; ++rg)
                Gp[(size_t)(gi_base + rg) * DT + gj] = f2bfu(acc[i][j][rg]);
        }
    }
}

extern "C" void kernel_launch(void* const* d_in, const int* in_sizes, int n_in,
                              void* d_out, int out_size, void* d_ws, size_t ws_size,
                              hipStream_t stream) {
    const float* V = (const float*)d_in[0];
    const float* Y = (const float*)d_in[1];
    float* out = (float*)d_out;

    char* ws = (char*)d_ws;
    float* s   = (float*)ws;                          // 2048 B
    float* rsd = (float*)(ws + 2048);                 // 524288 B

    const size_t XS_OFF = 2048 + 524288;              // 526336
    const size_t XS_BYTES = (size_t)BB * 256 * DT * 64 * 2;   // 83,886,080
    const size_t GP_BYTES = (size_t)BB * 2 * NCG * QSZ * 2;   // 26,214,400
    const size_t need2 = XS_OFF + XS_BYTES + GP_BYTES;        // ~110.6 MB
    const size_t need1 = XS_OFF + GP_BYTES;

    hipMemsetAsync(s, 0, 2048, stream);
    hipMemsetAsync(d_out, 0, sizeof(float), stream);

    colsum_kernel<<<dim3(32, BB), 256, 0, stream>>>(Y, s);
    rsd_kernel<<<2048, 256, 0, stream>>>(Y, s, rsd);

    if (ws_size >= need2) {
        unsigned short* Xs    = (unsigned short*)(ws + XS_OFF);
        unsigned short* Gpart = (unsigned short*)(ws + XS_OFF + XS_BYTES);
        xt2_kernel<<<dim3(256, 5, BB), 256, 0, stream>>>(V, Y, rsd, Xs);
        gram4_kernel<<<dim3(NCG, 2, BB), 512, 0, stream>>>(Xs, Gpart);
        loss_priv_kernel<<<dim3(25, 16), 256, 0, stream>>>(Gpart, out);
    } else if (ws_size >= need1) {
        unsigned short* Gpart = (unsigned short*)(ws + XS_OFF);
        gram_fb_kernel<<<dim3(NCG, 2, BB), 512, 0, stream>>>(V, Y, rsd, Gpart);
        loss_priv_kernel<<<dim3(25, 16), 256, 0, stream>>>(Gpart, out);
    }
}